// Round 20
// baseline (75.599 us; speedup 1.0000x reference)
//
#include <hip/hip_runtime.h>

typedef float f32x2 __attribute__((ext_vector_type(2)));
typedef float f32x4 __attribute__((ext_vector_type(4)));
typedef float f32x16 __attribute__((ext_vector_type(16)));
typedef _Float16 half8 __attribute__((ext_vector_type(8)));
typedef _Float16 half4 __attribute__((ext_vector_type(4)));
typedef unsigned int u32;
typedef u32 u32x4 __attribute__((ext_vector_type(4)));

#define S_LEN 2048
#define NHEAD 16
#define HDIM 64
#define BATCH 2
#define WINDOW 512
#define M2_FIX 5.770780163555852f   /* 4.0 * log2(e) */
#define LOG2E 1.4426950408889634f

#define GLDS16(gp, lp) __builtin_amdgcn_global_load_lds( \
    (const __attribute__((address_space(1))) void*)(gp), \
    (__attribute__((address_space(3))) void*)(lp), 16, 0, 0)

// Fragment-packed layouts (per bh = b*16+head, stride 131072 halfs):
//  Q/K tile t: [ch(4)][lane(64)][j(8)]  lane=((d>>3)&1)*32+(s&31), ch=d>>4, j=d&7
//  V   tile t: [sub(4)][lane(64)][j(8)] sub=(d>>5)*2+((s>>4)&1),
//                                       lane=((s>>3)&1)*32+(d&31), j=s&7

// ---------------- kernel 1: convert hs + W(q,k,v) f32 -> f16, 4x/thread -----
__global__ __launch_bounds__(256) void convert_kernel(
    const float4* __restrict__ hs, const float4* __restrict__ wq,
    const float4* __restrict__ wk, const float4* __restrict__ wv,
    _Float16* __restrict__ hsb, _Float16* __restrict__ wb) {
  const int base = blockIdx.x * 256 + threadIdx.x;
#pragma unroll
  for (int rep = 0; rep < 4; ++rep) {
    const int i = base + rep * 458752;
    float4 v;
    _Float16* dst;
    if (i < 1048576) {
      v = hs[i];
      dst = hsb + (size_t)i * 4;
    } else {
      int j = i - 1048576;
      if (j < 262144) v = wq[j];
      else if (j < 524288) v = wk[j - 262144];
      else v = wv[j - 524288];
      dst = wb + (size_t)j * 4;
    }
    half4 o;
    o[0] = (_Float16)v.x; o[1] = (_Float16)v.y;
    o[2] = (_Float16)v.z; o[3] = (_Float16)v.w;
    *(half4*)dst = o;
  }
}

// ---------------- kernel 2: QKV GEMM (r19 verbatim — frozen) ----------------
__global__ __launch_bounds__(512, 2) void qkv_gemm(
    const _Float16* __restrict__ A, const _Float16* __restrict__ W,
    const float* __restrict__ bq, const float* __restrict__ bk,
    const float* __restrict__ bv,
    _Float16* __restrict__ Qf, _Float16* __restrict__ Kf, _Float16* __restrict__ Vf) {
  __shared__ _Float16 sbuf[65536];   // 128KB: A[2][256][64] | B[2][256][64]
  const int tid = threadIdx.x;
  const int wv = tid >> 6;           // 0..7
  const int lane = tid & 63;
  const int g = lane >> 4;
  const int c = lane & 15;
  const int bid = blockIdx.x;        // 192 blocks: m = bid&15 -> same-m same XCD
  const int m0 = (bid & 15) * 256;
  const int n0 = (bid >> 4) * 256;
  const int wm = wv >> 2;            // 0,1  (m half)
  const int wn = wv & 3;             // 0..3 (n quarter)

  const int srow = tid >> 3;                       // 0..63
  const int sk = ((tid & 7) ^ ((tid >> 3) & 7)) * 8;
  const _Float16* aSrc = A + (size_t)(m0 + srow) * 1024 + sk;
  const _Float16* bSrc = W + (size_t)(n0 + srow) * 1024 + sk;
  char* const ldsB = (char*)&sbuf[0];

  auto STAGE_A = [&](int bf_, int k0, int grp) __attribute__((always_inline)) {
    GLDS16(aSrc + (size_t)grp * 65536 + k0,
           ldsB + bf_ * 32768 + grp * 8192 + tid * 16);
  };
  auto STAGE_B = [&](int bf_, int k0, int grp) __attribute__((always_inline)) {
    GLDS16(bSrc + (size_t)grp * 65536 + k0,
           ldsB + 65536 + bf_ * 32768 + grp * 8192 + tid * 16);
  };

  const int slot0 = ((0 * 4 + g) ^ (c & 7)) * 8;   // kk=0 chunk slot
  const int slot1 = ((4 + g) ^ (c & 7)) * 8;       // kk=1
  const int aRow = wm * 128 + c;
  const int bRow = wn * 64 + c;

  f32x4 acc[8][4];
#pragma unroll
  for (int i = 0; i < 8; ++i)
#pragma unroll
    for (int j = 0; j < 4; ++j) acc[i][j] = (f32x4){0.f, 0.f, 0.f, 0.f};

#pragma unroll
  for (int grp = 0; grp < 4; ++grp) STAGE_A(0, 0, grp);
#pragma unroll
  for (int grp = 0; grp < 4; ++grp) STAGE_B(0, 0, grp);
  asm volatile("s_waitcnt vmcnt(0)" ::: "memory");
  __builtin_amdgcn_sched_barrier(0);
  __builtin_amdgcn_s_barrier();

#define READA(dstv, ph)                                                       \
  {                                                                           \
    _Pragma("unroll") for (int mi = 0; mi < 2; ++mi) {                        \
      const int row = aRow + (2 * (ph) + mi) * 16;                            \
      dstv[mi][0] = *(const half8*)&sbuf[abase + row * 64 + slot0];           \
      dstv[mi][1] = *(const half8*)&sbuf[abase + row * 64 + slot1];           \
    }                                                                         \
  }
#define MFMAP(ph, srcv)                                                       \
  {                                                                           \
    __builtin_amdgcn_s_setprio(1);                                            \
    _Pragma("unroll") for (int nf = 0; nf < 4; ++nf)                          \
        _Pragma("unroll") for (int mi = 0; mi < 2; ++mi) {                    \
      acc[2 * (ph) + mi][nf] = __builtin_amdgcn_mfma_f32_16x16x32_f16(        \
          srcv[mi][0], bfr[nf][0], acc[2 * (ph) + mi][nf], 0, 0, 0);          \
      acc[2 * (ph) + mi][nf] = __builtin_amdgcn_mfma_f32_16x16x32_f16(        \
          srcv[mi][1], bfr[nf][1], acc[2 * (ph) + mi][nf], 0, 0, 0);          \
    }                                                                         \
    __builtin_amdgcn_s_setprio(0);                                            \
  }

  half8 bfr[4][2], aqA[2][2], aqB[2][2];
  for (int t = 0; t < 16; ++t) {
    const int bf = t & 1;
    const int abase = bf * 16384;
    const int bbase = 32768 + bf * 16384;
    const int kn = (t + 1) * 64;
    const bool st = t < 15;

#pragma unroll
    for (int nf = 0; nf < 4; ++nf) {
      bfr[nf][0] = *(const half8*)&sbuf[bbase + (bRow + nf * 16) * 64 + slot0];
      bfr[nf][1] = *(const half8*)&sbuf[bbase + (bRow + nf * 16) * 64 + slot1];
    }
    READA(aqA, 0);
    if (st) {
      STAGE_A(bf ^ 1, kn, 0); STAGE_A(bf ^ 1, kn, 1);
      STAGE_A(bf ^ 1, kn, 2); STAGE_A(bf ^ 1, kn, 3);
    }
    READA(aqB, 1);
    MFMAP(0, aqA);
    if (st) {
      STAGE_B(bf ^ 1, kn, 0); STAGE_B(bf ^ 1, kn, 1);
      STAGE_B(bf ^ 1, kn, 2); STAGE_B(bf ^ 1, kn, 3);
    }
    READA(aqA, 2);
    MFMAP(1, aqB);
    READA(aqB, 3);
    MFMAP(2, aqA);
    MFMAP(3, aqB);

    asm volatile("s_waitcnt vmcnt(0)" ::: "memory");
    __builtin_amdgcn_sched_barrier(0);
    __builtin_amdgcn_s_barrier();
  }

  const int nAbs = n0 + wn * 64;
  const int kind = nAbs >> 10;              // 0=Q 1=K 2=V
  const int nb = nAbs & 1023;
  const int head = nb >> 6;
  const float* bias = kind == 0 ? bq : (kind == 1 ? bk : bv);
  _Float16* dst = kind == 0 ? Qf : (kind == 1 ? Kf : Vf);
  _Float16* ob = &sbuf[wv * 8192];

  if (kind < 2) {
    const float scl = kind == 0 ? (0.125f * LOG2E) : 1.0f;
#pragma unroll
    for (int nf = 0; nf < 4; ++nf) {
      const int d = nf * 16 + c;
      const float bsv = bias[nb + d];
      const int base = nf * 512 + ((c >> 3) & 1) * 256 + (c & 7);
#pragma unroll
      for (int mf = 0; mf < 8; ++mf) {
#pragma unroll
        for (int r = 0; r < 4; ++r) {
          ob[(mf >> 1) * 2048 + base + (mf & 1) * 128 + g * 32 + r * 8] =
              (_Float16)((acc[mf][nf][r] + bsv) * scl);
        }
      }
    }
  } else {
#pragma unroll
    for (int nf = 0; nf < 4; ++nf) {
      const int d = nf * 16 + c;
      const float bsv = bias[nb + d];
#pragma unroll
      for (int mf = 0; mf < 8; ++mf) {
        half4 v4;
#pragma unroll
        for (int r = 0; r < 4; ++r) v4[r] = (_Float16)(acc[mf][nf][r] + bsv);
        *(half4*)&ob[(mf >> 1) * 2048 + ((nf >> 1) * 2 + (mf & 1)) * 512 +
                     ((g >> 1) * 32 + (nf & 1) * 16 + c) * 8 + (g & 1) * 4] = v4;
      }
    }
  }

  const int mRow = m0 + wm * 128;
  const int bI = mRow >> 11;
  const size_t gbase = (size_t)(bI * NHEAD + head) * 131072 +
                       (size_t)((mRow & 2047) >> 5) * 2048;
#pragma unroll
  for (int i = 0; i < 16; ++i) {
    half8 v = *(const half8*)&ob[i * 512 + lane * 8];
    *(half8*)&dst[gbase + i * 512 + lane * 8] = v;
  }
}

// ---------------- kernel 3: windowed flash attention, 8-wave k-split --------
// 512 threads = 8 waves per (bh, 32-q strip); wave w takes k-tiles t%8==w.
// Halves the longest per-wave serial chain vs 4-wave split.
__global__ __launch_bounds__(512) void attn_kernel(
    const _Float16* __restrict__ Qf, const _Float16* __restrict__ Kf,
    const _Float16* __restrict__ Vf, const float* __restrict__ amask,
    float* __restrict__ out) {
  __shared__ _Float16 obuf[8][32][72];
  __shared__ float lbuf[8][32];
  const int tid = threadIdx.x;
  const int w = tid >> 6;           // 0..7
  const int lane = tid & 63;
  const int q31 = lane & 31;
  const int h = lane >> 5;
  const int bid = blockIdx.x;
  const int bh = bid & 31;
  const int idx = 63 - (bid >> 5);  // longest strips launch first
  const int i0 = idx * 32;
  const int bI = bh >> 4;
  const int head = bh & 15;

  const _Float16* Qh = Qf + (size_t)bh * 131072;
  const _Float16* Kh = Kf + (size_t)bh * 131072;
  const _Float16* Vh = Vf + (size_t)bh * 131072;
  const float* am = amask + (size_t)bI * S_LEN;

  const int q = i0 + q31;
  const int hiq = (q <= WINDOW) ? q : (q - WINDOW - 1);
  const int last = i0 + 31;
  const int himax = (last <= WINDOW) ? last
                    : ((i0 <= WINDOW) ? WINDOW : (last - WINDOW - 1));
  const int hiq_min = (last <= WINDOW) ? i0
                      : ((i0 > WINDOW) ? (i0 - WINDOW - 1) : 0);
  const int ntiles = (himax >> 5) + 1;
  const int nfull = (hiq_min + 1) >> 5;
  const int lim = hiq - 4 * h;

  half8 qf[4];
#pragma unroll
  for (int ch = 0; ch < 4; ++ch)
    qf[ch] = *(const half8*)&Qh[(size_t)idx * 2048 + ch * 512 + lane * 8];

  f32x16 m2init;
#pragma unroll
  for (int r = 0; r < 16; ++r) m2init[r] = -M2_FIX;
  f32x16 oacc0 = {}, oacc1 = {};
  f32x2 lp[4];
#pragma unroll
  for (int r = 0; r < 4; ++r) lp[r] = (f32x2){0.f, 0.f};

  auto computeTile = [&](half8 k0, half8 k1, half8 k2, half8 k3,
                         half8 vf0, half8 vf1, half8 vf2, half8 vf3,
                         f32x4 am0, f32x4 am1, f32x4 am2, f32x4 am3, int t)
      __attribute__((always_inline)) {
    const int j0 = t * 32;
    f32x4 amv[4] = {am0, am1, am2, am3};

    __builtin_amdgcn_s_setprio(1);
    f32x16 st = __builtin_amdgcn_mfma_f32_32x32x16_f16(k0, qf[0], m2init, 0, 0, 0);
    st = __builtin_amdgcn_mfma_f32_32x32x16_f16(k1, qf[1], st, 0, 0, 0);
    st = __builtin_amdgcn_mfma_f32_32x32x16_f16(k2, qf[2], st, 0, 0, 0);
    st = __builtin_amdgcn_mfma_f32_32x32x16_f16(k3, qf[3], st, 0, 0, 0);
    __builtin_amdgcn_s_setprio(0);

    float p[16];
#pragma unroll
    for (int r = 0; r < 16; ++r)
      p[r] = __builtin_fmaf(amv[r >> 2][r & 3], LOG2E, st[r]);
    if (t >= nfull) {
      const int lm = lim - j0;
#pragma unroll
      for (int r = 0; r < 16; ++r) {
        const int off = (r & 3) + 8 * (r >> 2);
        p[r] = (off <= lm) ? p[r] : -3e38f;
      }
    }
#pragma unroll
    for (int r = 0; r < 16; ++r) p[r] = __builtin_amdgcn_exp2f(p[r]);
#pragma unroll
    for (int j = 0; j < 4; ++j) {
      lp[j] += (f32x2){p[2 * j], p[2 * j + 1]};
      lp[j] += (f32x2){p[8 + 2 * j], p[9 + 2 * j]};
    }

    u32 pk[8];
#pragma unroll
    for (int r = 0; r < 8; ++r) {
      auto c2 = __builtin_amdgcn_cvt_pkrtz(p[2 * r], p[2 * r + 1]);
      pk[r] = __builtin_bit_cast(u32, c2);
    }
    u32 a0 = pk[0], b0 = pk[2];
    u32 a1 = pk[1], b1 = pk[3];
    u32 a2 = pk[4], b2 = pk[6];
    u32 a3 = pk[5], b3 = pk[7];
    asm("v_permlane32_swap_b32 %0, %1" : "+v"(a0), "+v"(b0));
    asm("v_permlane32_swap_b32 %0, %1" : "+v"(a1), "+v"(b1));
    asm("v_permlane32_swap_b32 %0, %1" : "+v"(a2), "+v"(b2));
    asm("v_permlane32_swap_b32 %0, %1" : "+v"(a3), "+v"(b3));
    const half8 pf0 = __builtin_bit_cast(half8, (u32x4){a0, a1, b0, b1});
    const half8 pf1 = __builtin_bit_cast(half8, (u32x4){a2, a3, b2, b3});

    __builtin_amdgcn_s_setprio(1);
    oacc0 = __builtin_amdgcn_mfma_f32_32x32x16_f16(vf0, pf0, oacc0, 0, 0, 0);
    oacc0 = __builtin_amdgcn_mfma_f32_32x32x16_f16(vf1, pf1, oacc0, 0, 0, 0);
    oacc1 = __builtin_amdgcn_mfma_f32_32x32x16_f16(vf2, pf0, oacc1, 0, 0, 0);
    oacc1 = __builtin_amdgcn_mfma_f32_32x32x16_f16(vf3, pf1, oacc1, 0, 0, 0);
    __builtin_amdgcn_s_setprio(0);
  };

#define LOADALL(k0, k1, k2, k3, v0, v1, v2, v3, a0_, a1_, a2_, a3_, tt)  \
  {                                                                      \
    const _Float16* kt = Kh + (size_t)(tt) * 2048 + lane * 8;            \
    const _Float16* vt = Vh + (size_t)(tt) * 2048 + lane * 8;            \
    const float* at = am + (tt) * 32 + 4 * h;                            \
    k0 = *(const half8*)&kt[0];                                          \
    k1 = *(const half8*)&kt[512];                                        \
    k2 = *(const half8*)&kt[1024];                                       \
    k3 = *(const half8*)&kt[1536];                                       \
    v0 = *(const half8*)&vt[0];                                          \
    v1 = *(const half8*)&vt[512];                                        \
    v2 = *(const half8*)&vt[1024];                                       \
    v3 = *(const half8*)&vt[1536];                                       \
    a0_ = *(const f32x4*)&at[0];                                         \
    a1_ = *(const f32x4*)&at[8];                                         \
    a2_ = *(const f32x4*)&at[16];                                        \
    a3_ = *(const f32x4*)&at[24];                                        \
  }

  int t = w;
  if (t < ntiles) {
    half8 k0, k1, k2, k3, v0, v1, v2, v3;
    f32x4 a0, a1, a2, a3;
    LOADALL(k0, k1, k2, k3, v0, v1, v2, v3, a0, a1, a2, a3, t);
    int tn = t + 8;
    while (tn < ntiles) {
      half8 n0, n1, n2, n3, u0, u1, u2, u3;
      f32x4 e0, e1, e2, e3;
      LOADALL(n0, n1, n2, n3, u0, u1, u2, u3, e0, e1, e2, e3, tn);
      computeTile(k0, k1, k2, k3, v0, v1, v2, v3, a0, a1, a2, a3, t);
      k0 = n0; k1 = n1; k2 = n2; k3 = n3;
      v0 = u0; v1 = u1; v2 = u2; v3 = u3;
      a0 = e0; a1 = e1; a2 = e2; a3 = e3;
      t = tn;
      tn += 8;
    }
    computeTile(k0, k1, k2, k3, v0, v1, v2, v3, a0, a1, a2, a3, t);
  }

  f32x2 s2 = (lp[0] + lp[1]) + (lp[2] + lp[3]);
  float lw = s2[0] + s2[1];
  lw += __shfl_xor(lw, 32);
  if (h == 0) lbuf[w][q31] = lw;
#pragma unroll
  for (int j = 0; j < 4; ++j) {
    half4 h0, h1;
#pragma unroll
    for (int e = 0; e < 4; ++e) {
      h0[e] = (_Float16)oacc0[4 * j + e];
      h1[e] = (_Float16)oacc1[4 * j + e];
    }
    *(half4*)&obuf[w][q31][4 * h + 8 * j]      = h0;
    *(half4*)&obuf[w][q31][32 + 4 * h + 8 * j] = h1;
  }
  __syncthreads();

  // merge 8 wave-partials: thread handles (q=mq, 4 d at md)
  const int mq = tid >> 4;            // 0..31
  const int md = (tid & 15) * 4;      // 0..60
  float lt = 0.f;
#pragma unroll
  for (int w8 = 0; w8 < 8; ++w8) lt += lbuf[w8][mq];
  float s[4] = {0.f, 0.f, 0.f, 0.f};
#pragma unroll
  for (int w8 = 0; w8 < 8; ++w8) {
    half4 pw = *(const half4*)&obuf[w8][mq][md];
#pragma unroll
    for (int e = 0; e < 4; ++e) s[e] += (float)pw[e];
  }
  const float inv = 1.0f / lt;
  float4 s0;
  s0.x = s[0] * inv; s0.y = s[1] * inv; s0.z = s[2] * inv; s0.w = s[3] * inv;
  float* op = out + ((size_t)(bI * S_LEN + i0 + mq)) * 1024 + head * 64 + md;
  *(float4*)op = s0;
}

// ---------------- launch --------------------------------------------------
extern "C" void kernel_launch(void* const* d_in, const int* in_sizes, int n_in,
                              void* d_out, int out_size, void* d_ws, size_t ws_size,
                              hipStream_t stream) {
  const float* hs = (const float*)d_in[0];
  const float* am = (const float*)d_in[1];
  const float* Wq = (const float*)d_in[2];
  const float* bq = (const float*)d_in[3];
  const float* Wk = (const float*)d_in[4];
  const float* bk = (const float*)d_in[5];
  const float* Wv = (const float*)d_in[6];
  const float* bv = (const float*)d_in[7];
  float* out = (float*)d_out;

  char* ws = (char*)d_ws;
  _Float16* hsb = (_Float16*)(ws);
  _Float16* wb  = (_Float16*)(ws + 8388608);
  _Float16* Qf  = (_Float16*)(ws + 14680064);
  _Float16* Kf  = (_Float16*)(ws + 23068672);
  _Float16* Vf  = (_Float16*)(ws + 31457280);

  convert_kernel<<<1792, 256, 0, stream>>>(
      (const float4*)hs, (const float4*)Wq, (const float4*)Wk, (const float4*)Wv, hsb, wb);
  qkv_gemm<<<192, 512, 0, stream>>>(hsb, wb, bq, bk, bv, Qf, Kf, Vf);
  attn_kernel<<<2048, 512, 0, stream>>>(Qf, Kf, Vf, am, out);
}

// Round 21
// 75.504 us; speedup vs baseline: 1.0013x; 1.0013x over previous
//
#include <hip/hip_runtime.h>

typedef float f32x2 __attribute__((ext_vector_type(2)));
typedef float f32x4 __attribute__((ext_vector_type(4)));
typedef float f32x16 __attribute__((ext_vector_type(16)));
typedef _Float16 half8 __attribute__((ext_vector_type(8)));
typedef _Float16 half4 __attribute__((ext_vector_type(4)));
typedef unsigned int u32;
typedef u32 u32x4 __attribute__((ext_vector_type(4)));

#define S_LEN 2048
#define NHEAD 16
#define HDIM 64
#define BATCH 2
#define WINDOW 512
#define M2_FIX 5.770780163555852f   /* 4.0 * log2(e) */
#define LOG2E 1.4426950408889634f

#define GLDS16(gp, lp) __builtin_amdgcn_global_load_lds( \
    (const __attribute__((address_space(1))) void*)(gp), \
    (__attribute__((address_space(3))) void*)(lp), 16, 0, 0)

// Fragment-packed layouts (per bh = b*16+head, stride 131072 halfs):
//  Q/K tile t: [ch(4)][lane(64)][j(8)]  lane=((d>>3)&1)*32+(s&31), ch=d>>4, j=d&7
//  V   tile t: [sub(4)][lane(64)][j(8)] sub=(d>>5)*2+((s>>4)&1),
//                                       lane=((s>>3)&1)*32+(d&31), j=s&7

// ---------------- kernel 1: convert hs + W(q,k,v) f32 -> f16 (r19) ----------
__global__ __launch_bounds__(256) void convert_kernel(
    const float4* __restrict__ hs, const float4* __restrict__ wq,
    const float4* __restrict__ wk, const float4* __restrict__ wv,
    _Float16* __restrict__ hsb, _Float16* __restrict__ wb) {
  int i = blockIdx.x * 256 + threadIdx.x;
  float4 v;
  _Float16* dst;
  if (i < 1048576) {
    v = hs[i];
    dst = hsb + (size_t)i * 4;
  } else {
    int j = i - 1048576;
    if (j < 262144) v = wq[j];
    else if (j < 524288) v = wk[j - 262144];
    else v = wv[j - 524288];
    dst = wb + (size_t)j * 4;
  }
  half4 o;
  o[0] = (_Float16)v.x; o[1] = (_Float16)v.y;
  o[2] = (_Float16)v.z; o[3] = (_Float16)v.w;
  *(half4*)dst = o;
}

// ---------------- kernel 2: QKV GEMM, 128x128, 512 thr, 2 blocks/CU ---------
// 768 blocks = 3 full rounds over 256 CUs; 64KB LDS -> 2 blocks/CU ->
// 4 waves/SIMD TLP. Wave tile 64x32 (acc 4x2). r19 pipeline skeleton:
// stage-early, one vmcnt(0)+raw-barrier per K-tile, no per-phase drains.
__global__ __launch_bounds__(512, 4) void qkv_gemm(
    const _Float16* __restrict__ A, const _Float16* __restrict__ W,
    const float* __restrict__ bq, const float* __restrict__ bk,
    const float* __restrict__ bv,
    _Float16* __restrict__ Qf, _Float16* __restrict__ Kf, _Float16* __restrict__ Vf) {
  __shared__ _Float16 sbuf[32768];   // 64KB: 2 x (A[128][64] | B[128][64])
  const int tid = threadIdx.x;
  const int wv = tid >> 6;           // 0..7
  const int lane = tid & 63;
  const int g = lane >> 4;
  const int c = lane & 15;
  const int bid = blockIdx.x;        // m = bid&31 -> same-m same-XCD (round robin)
  const int m0 = (bid & 31) * 128;
  const int n0 = (bid >> 5) * 128;
  const int wm = wv >> 2;            // 0,1  (m half, 64 rows)
  const int wn = wv & 3;             // 0..3 (n quarter, 32 cols)

  // staging: thread covers row tid>>3 of each 64-row group, swizzled k-chunk
  const int sk = ((tid & 7) ^ ((tid >> 3) & 7)) * 8;
  const _Float16* aSrc = A + (size_t)(m0 + (tid >> 3)) * 1024 + sk;
  const _Float16* bSrc = W + (size_t)(n0 + (tid >> 3)) * 1024 + sk;
  char* const ldsB = (char*)&sbuf[0];

  auto STAGE_A = [&](int bf_, int k0, int grp) __attribute__((always_inline)) {
    GLDS16(aSrc + (size_t)grp * 65536 + k0,
           ldsB + bf_ * 32768 + grp * 8192 + tid * 16);
  };
  auto STAGE_B = [&](int bf_, int k0, int grp) __attribute__((always_inline)) {
    GLDS16(bSrc + (size_t)grp * 65536 + k0,
           ldsB + bf_ * 32768 + 16384 + grp * 8192 + tid * 16);
  };

  const int slot0 = ((g) ^ (c & 7)) * 8;       // kk=0 chunk slot
  const int slot1 = ((4 + g) ^ (c & 7)) * 8;   // kk=1
  const int aRow = wm * 64 + c;
  const int bRow = wn * 32 + c;

  f32x4 acc[4][2];
#pragma unroll
  for (int i = 0; i < 4; ++i)
#pragma unroll
    for (int j = 0; j < 2; ++j) acc[i][j] = (f32x4){0.f, 0.f, 0.f, 0.f};

  // prologue: stage tile 0 fully, drain, barrier
  STAGE_A(0, 0, 0); STAGE_A(0, 0, 1);
  STAGE_B(0, 0, 0); STAGE_B(0, 0, 1);
  asm volatile("s_waitcnt vmcnt(0)" ::: "memory");
  __builtin_amdgcn_sched_barrier(0);
  __builtin_amdgcn_s_barrier();

  half8 bfr[2][2], af[4][2];
  for (int t = 0; t < 16; ++t) {
    const int bf = t & 1;
    const int abase = bf * 16384;
    const int bbase = bf * 16384 + 8192;
    const int kn = (t + 1) * 64;
    const bool st = t < 15;

    // B frags (whole tile) + A frags mf 0..1
#pragma unroll
    for (int nf = 0; nf < 2; ++nf) {
      bfr[nf][0] = *(const half8*)&sbuf[bbase + (bRow + nf * 16) * 64 + slot0];
      bfr[nf][1] = *(const half8*)&sbuf[bbase + (bRow + nf * 16) * 64 + slot1];
    }
#pragma unroll
    for (int mf = 0; mf < 2; ++mf) {
      const int row = aRow + mf * 16;
      af[mf][0] = *(const half8*)&sbuf[abase + row * 64 + slot0];
      af[mf][1] = *(const half8*)&sbuf[abase + row * 64 + slot1];
    }
    if (st) { STAGE_A(bf ^ 1, kn, 0); STAGE_A(bf ^ 1, kn, 1); }
#pragma unroll
    for (int mf = 2; mf < 4; ++mf) {
      const int row = aRow + mf * 16;
      af[mf][0] = *(const half8*)&sbuf[abase + row * 64 + slot0];
      af[mf][1] = *(const half8*)&sbuf[abase + row * 64 + slot1];
    }
    __builtin_amdgcn_s_setprio(1);
#pragma unroll
    for (int nf = 0; nf < 2; ++nf)
#pragma unroll
      for (int mf = 0; mf < 2; ++mf) {
        acc[mf][nf] = __builtin_amdgcn_mfma_f32_16x16x32_f16(af[mf][0], bfr[nf][0], acc[mf][nf], 0, 0, 0);
        acc[mf][nf] = __builtin_amdgcn_mfma_f32_16x16x32_f16(af[mf][1], bfr[nf][1], acc[mf][nf], 0, 0, 0);
      }
    __builtin_amdgcn_s_setprio(0);
    if (st) { STAGE_B(bf ^ 1, kn, 0); STAGE_B(bf ^ 1, kn, 1); }
    __builtin_amdgcn_s_setprio(1);
#pragma unroll
    for (int nf = 0; nf < 2; ++nf)
#pragma unroll
      for (int mf = 2; mf < 4; ++mf) {
        acc[mf][nf] = __builtin_amdgcn_mfma_f32_16x16x32_f16(af[mf][0], bfr[nf][0], acc[mf][nf], 0, 0, 0);
        acc[mf][nf] = __builtin_amdgcn_mfma_f32_16x16x32_f16(af[mf][1], bfr[nf][1], acc[mf][nf], 0, 0, 0);
      }
    __builtin_amdgcn_s_setprio(0);

    asm volatile("s_waitcnt vmcnt(0)" ::: "memory");   // tile t+1 landed
    __builtin_amdgcn_sched_barrier(0);
    __builtin_amdgcn_s_barrier();                       // dbuf safety
  }

  // ---- epilogue: per-wave 4KB LDS bounce, 4x 1KB contiguous stores ----
  const int nAbs = n0 + wn * 32;
  const int kind = nAbs >> 10;              // 0=Q 1=K 2=V
  const int nb = nAbs & 1023;               // col base within kind
  const int head = (nb >> 6) & 15;
  const int halfsel = wn & 1;               // which 32-col half of the head
  const float* bias = kind == 0 ? bq : (kind == 1 ? bk : bv);
  _Float16* dst = kind == 0 ? Qf : (kind == 1 ? Kf : Vf);
  _Float16* ob = &sbuf[wv * 2048];

  if (kind < 2) {
    const float scl = kind == 0 ? (0.125f * LOG2E) : 1.0f;
#pragma unroll
    for (int nf = 0; nf < 2; ++nf) {
      const float bsv = bias[nb + nf * 16 + c];
#pragma unroll
      for (int mf = 0; mf < 4; ++mf) {
#pragma unroll
        for (int r = 0; r < 4; ++r) {
          ob[(mf >> 1) * 1024 + nf * 512 + ((c >> 3) & 1) * 256 +
             ((mf & 1) * 16 + g * 4 + r) * 8 + (c & 7)] =
              (_Float16)((acc[mf][nf][r] + bsv) * scl);
        }
      }
    }
  } else {
#pragma unroll
    for (int nf = 0; nf < 2; ++nf) {
      const float bsv = bias[nb + nf * 16 + c];
#pragma unroll
      for (int mf = 0; mf < 4; ++mf) {
        half4 v4;
#pragma unroll
        for (int r = 0; r < 4; ++r) v4[r] = (_Float16)(acc[mf][nf][r] + bsv);
        *(half4*)&ob[(mf >> 1) * 1024 + (mf & 1) * 512 + (g >> 1) * 256 +
                     (nf * 16 + c) * 8 + (g & 1) * 4] = v4;
      }
    }
  }

  const int mRow = m0 + wm * 64;
  const int bI = mRow >> 11;
  const size_t gbase = (size_t)(bI * NHEAD + head) * 131072 +
                       (size_t)((mRow & 2047) >> 5) * 2048 + halfsel * 1024;
#pragma unroll
  for (int st2 = 0; st2 < 2; ++st2)
#pragma unroll
    for (int i2 = 0; i2 < 2; ++i2) {
      half8 v = *(const half8*)&ob[st2 * 1024 + i2 * 512 + lane * 8];
      *(half8*)&dst[gbase + st2 * 2048 + i2 * 512 + lane * 8] = v;
    }
}

// ---------------- kernel 3: windowed flash attention (r13/r19 verbatim) -----
__global__ __launch_bounds__(256) void attn_kernel(
    const _Float16* __restrict__ Qf, const _Float16* __restrict__ Kf,
    const _Float16* __restrict__ Vf, const float* __restrict__ amask,
    float* __restrict__ out) {
  __shared__ _Float16 obuf[4][32][72];
  __shared__ float lbuf[4][32];
  const int tid = threadIdx.x;
  const int w = tid >> 6;
  const int lane = tid & 63;
  const int q31 = lane & 31;
  const int h = lane >> 5;
  const int bid = blockIdx.x;
  const int bh = bid & 31;
  const int idx = 63 - (bid >> 5);  // longest strips launch first
  const int i0 = idx * 32;
  const int bI = bh >> 4;
  const int head = bh & 15;

  const _Float16* Qh = Qf + (size_t)bh * 131072;
  const _Float16* Kh = Kf + (size_t)bh * 131072;
  const _Float16* Vh = Vf + (size_t)bh * 131072;
  const float* am = amask + (size_t)bI * S_LEN;

  const int q = i0 + q31;
  const int hiq = (q <= WINDOW) ? q : (q - WINDOW - 1);
  const int last = i0 + 31;
  const int himax = (last <= WINDOW) ? last
                    : ((i0 <= WINDOW) ? WINDOW : (last - WINDOW - 1));
  const int hiq_min = (last <= WINDOW) ? i0
                      : ((i0 > WINDOW) ? (i0 - WINDOW - 1) : 0);
  const int ntiles = (himax >> 5) + 1;
  const int nfull = (hiq_min + 1) >> 5;
  const int lim = hiq - 4 * h;

  half8 qf[4];
#pragma unroll
  for (int ch = 0; ch < 4; ++ch)
    qf[ch] = *(const half8*)&Qh[(size_t)idx * 2048 + ch * 512 + lane * 8];

  f32x16 m2init;
#pragma unroll
  for (int r = 0; r < 16; ++r) m2init[r] = -M2_FIX;
  f32x16 oacc0 = {}, oacc1 = {};
  f32x2 lp[4];
#pragma unroll
  for (int r = 0; r < 4; ++r) lp[r] = (f32x2){0.f, 0.f};

  auto computeTile = [&](half8 k0, half8 k1, half8 k2, half8 k3,
                         half8 vf0, half8 vf1, half8 vf2, half8 vf3,
                         f32x4 am0, f32x4 am1, f32x4 am2, f32x4 am3, int t)
      __attribute__((always_inline)) {
    const int j0 = t * 32;
    f32x4 amv[4] = {am0, am1, am2, am3};

    __builtin_amdgcn_s_setprio(1);
    f32x16 st = __builtin_amdgcn_mfma_f32_32x32x16_f16(k0, qf[0], m2init, 0, 0, 0);
    st = __builtin_amdgcn_mfma_f32_32x32x16_f16(k1, qf[1], st, 0, 0, 0);
    st = __builtin_amdgcn_mfma_f32_32x32x16_f16(k2, qf[2], st, 0, 0, 0);
    st = __builtin_amdgcn_mfma_f32_32x32x16_f16(k3, qf[3], st, 0, 0, 0);
    __builtin_amdgcn_s_setprio(0);

    float p[16];
#pragma unroll
    for (int r = 0; r < 16; ++r)
      p[r] = __builtin_fmaf(amv[r >> 2][r & 3], LOG2E, st[r]);
    if (t >= nfull) {
      const int lm = lim - j0;
#pragma unroll
      for (int r = 0; r < 16; ++r) {
        const int off = (r & 3) + 8 * (r >> 2);
        p[r] = (off <= lm) ? p[r] : -3e38f;
      }
    }
#pragma unroll
    for (int r = 0; r < 16; ++r) p[r] = __builtin_amdgcn_exp2f(p[r]);
#pragma unroll
    for (int j = 0; j < 4; ++j) {
      lp[j] += (f32x2){p[2 * j], p[2 * j + 1]};
      lp[j] += (f32x2){p[8 + 2 * j], p[9 + 2 * j]};
    }

    u32 pk[8];
#pragma unroll
    for (int r = 0; r < 8; ++r) {
      auto c2 = __builtin_amdgcn_cvt_pkrtz(p[2 * r], p[2 * r + 1]);
      pk[r] = __builtin_bit_cast(u32, c2);
    }
    u32 a0 = pk[0], b0 = pk[2];
    u32 a1 = pk[1], b1 = pk[3];
    u32 a2 = pk[4], b2 = pk[6];
    u32 a3 = pk[5], b3 = pk[7];
    asm("v_permlane32_swap_b32 %0, %1" : "+v"(a0), "+v"(b0));
    asm("v_permlane32_swap_b32 %0, %1" : "+v"(a1), "+v"(b1));
    asm("v_permlane32_swap_b32 %0, %1" : "+v"(a2), "+v"(b2));
    asm("v_permlane32_swap_b32 %0, %1" : "+v"(a3), "+v"(b3));
    const half8 pf0 = __builtin_bit_cast(half8, (u32x4){a0, a1, b0, b1});
    const half8 pf1 = __builtin_bit_cast(half8, (u32x4){a2, a3, b2, b3});

    __builtin_amdgcn_s_setprio(1);
    oacc0 = __builtin_amdgcn_mfma_f32_32x32x16_f16(vf0, pf0, oacc0, 0, 0, 0);
    oacc0 = __builtin_amdgcn_mfma_f32_32x32x16_f16(vf1, pf1, oacc0, 0, 0, 0);
    oacc1 = __builtin_amdgcn_mfma_f32_32x32x16_f16(vf2, pf0, oacc1, 0, 0, 0);
    oacc1 = __builtin_amdgcn_mfma_f32_32x32x16_f16(vf3, pf1, oacc1, 0, 0, 0);
    __builtin_amdgcn_s_setprio(0);
  };

#define LOADALL(k0, k1, k2, k3, v0, v1, v2, v3, a0_, a1_, a2_, a3_, tt)  \
  {                                                                      \
    const _Float16* kt = Kh + (size_t)(tt) * 2048 + lane * 8;            \
    const _Float16* vt = Vh + (size_t)(tt) * 2048 + lane * 8;            \
    const float* at = am + (tt) * 32 + 4 * h;                            \
    k0 = *(const half8*)&kt[0];                                          \
    k1 = *(const half8*)&kt[512];                                        \
    k2 = *(const half8*)&kt[1024];                                       \
    k3 = *(const half8*)&kt[1536];                                       \
    v0 = *(const half8*)&vt[0];                                          \
    v1 = *(const half8*)&vt[512];                                        \
    v2 = *(const half8*)&vt[1024];                                       \
    v3 = *(const half8*)&vt[1536];                                       \
    a0_ = *(const f32x4*)&at[0];                                         \
    a1_ = *(const f32x4*)&at[8];                                         \
    a2_ = *(const f32x4*)&at[16];                                        \
    a3_ = *(const f32x4*)&at[24];                                        \
  }

  int t = w;
  if (t < ntiles) {
    half8 k0, k1, k2, k3, v0, v1, v2, v3;
    f32x4 a0, a1, a2, a3;
    LOADALL(k0, k1, k2, k3, v0, v1, v2, v3, a0, a1, a2, a3, t);
    int tn = t + 4;
    while (tn < ntiles) {
      half8 n0, n1, n2, n3, u0, u1, u2, u3;
      f32x4 e0, e1, e2, e3;
      LOADALL(n0, n1, n2, n3, u0, u1, u2, u3, e0, e1, e2, e3, tn);
      computeTile(k0, k1, k2, k3, v0, v1, v2, v3, a0, a1, a2, a3, t);
      k0 = n0; k1 = n1; k2 = n2; k3 = n3;
      v0 = u0; v1 = u1; v2 = u2; v3 = u3;
      a0 = e0; a1 = e1; a2 = e2; a3 = e3;
      t = tn;
      tn += 4;
    }
    computeTile(k0, k1, k2, k3, v0, v1, v2, v3, a0, a1, a2, a3, t);
  }

  f32x2 s2 = (lp[0] + lp[1]) + (lp[2] + lp[3]);
  float lw = s2[0] + s2[1];
  lw += __shfl_xor(lw, 32);
  if (h == 0) lbuf[w][q31] = lw;
#pragma unroll
  for (int j = 0; j < 4; ++j) {
    half4 h0, h1;
#pragma unroll
    for (int e = 0; e < 4; ++e) {
      h0[e] = (_Float16)oacc0[4 * j + e];
      h1[e] = (_Float16)oacc1[4 * j + e];
    }
    *(half4*)&obuf[w][q31][4 * h + 8 * j]      = h0;
    *(half4*)&obuf[w][q31][32 + 4 * h + 8 * j] = h1;
  }
  __syncthreads();

  const int mq = tid >> 3;
  const int md = (tid & 7) * 8;
  const float lt = (lbuf[0][mq] + lbuf[1][mq]) + (lbuf[2][mq] + lbuf[3][mq]);
  float s[8];
  half8 p0 = *(const half8*)&obuf[0][mq][md];
#pragma unroll
  for (int e = 0; e < 8; ++e) s[e] = (float)p0[e];
#pragma unroll
  for (int w4 = 1; w4 < 4; ++w4) {
    half8 pw = *(const half8*)&obuf[w4][mq][md];
#pragma unroll
    for (int e = 0; e < 8; ++e) s[e] += (float)pw[e];
  }
  const float inv = 1.0f / lt;
  float4 s0, s1;
  s0.x = s[0] * inv; s0.y = s[1] * inv; s0.z = s[2] * inv; s0.w = s[3] * inv;
  s1.x = s[4] * inv; s1.y = s[5] * inv; s1.z = s[6] * inv; s1.w = s[7] * inv;
  float* op = out + ((size_t)(bI * S_LEN + i0 + mq)) * 1024 + head * 64 + md;
  *(float4*)op = s0;
  *(float4*)(op + 4) = s1;
}

// ---------------- launch --------------------------------------------------
extern "C" void kernel_launch(void* const* d_in, const int* in_sizes, int n_in,
                              void* d_out, int out_size, void* d_ws, size_t ws_size,
                              hipStream_t stream) {
  const float* hs = (const float*)d_in[0];
  const float* am = (const float*)d_in[1];
  const float* Wq = (const float*)d_in[2];
  const float* bq = (const float*)d_in[3];
  const float* Wk = (const float*)d_in[4];
  const float* bk = (const float*)d_in[5];
  const float* Wv = (const float*)d_in[6];
  const float* bv = (const float*)d_in[7];
  float* out = (float*)d_out;

  char* ws = (char*)d_ws;
  _Float16* hsb = (_Float16*)(ws);
  _Float16* wb  = (_Float16*)(ws + 8388608);
  _Float16* Qf  = (_Float16*)(ws + 14680064);
  _Float16* Kf  = (_Float16*)(ws + 23068672);
  _Float16* Vf  = (_Float16*)(ws + 31457280);

  convert_kernel<<<7168, 256, 0, stream>>>(
      (const float4*)hs, (const float4*)Wq, (const float4*)Wk, (const float4*)Wv, hsb, wb);
  qkv_gemm<<<768, 512, 0, stream>>>(hsb, wb, bq, bk, bv, Qf, Kf, Vf);
  attn_kernel<<<2048, 256, 0, stream>>>(Qf, Kf, Vf, am, out);
}

// Round 22
// 69.539 us; speedup vs baseline: 1.0871x; 1.0858x over previous
//
#include <hip/hip_runtime.h>

typedef float f32x2 __attribute__((ext_vector_type(2)));
typedef float f32x4 __attribute__((ext_vector_type(4)));
typedef float f32x16 __attribute__((ext_vector_type(16)));
typedef _Float16 half8 __attribute__((ext_vector_type(8)));
typedef _Float16 half4 __attribute__((ext_vector_type(4)));
typedef unsigned int u32;
typedef u32 u32x4 __attribute__((ext_vector_type(4)));

#define S_LEN 2048
#define NHEAD 16
#define HDIM 64
#define BATCH 2
#define WINDOW 512
#define M2_FIX 5.770780163555852f   /* 4.0 * log2(e) */
#define LOG2E 1.4426950408889634f

#define GLDS16(gp, lp) __builtin_amdgcn_global_load_lds( \
    (const __attribute__((address_space(1))) void*)(gp), \
    (__attribute__((address_space(3))) void*)(lp), 16, 0, 0)

// Fragment-packed layouts (per bh = b*16+head, stride 131072 halfs):
//  Q/K tile t: [ch(4)][lane(64)][j(8)]  lane=((d>>3)&1)*32+(s&31), ch=d>>4, j=d&7
//  V   tile t: [sub(4)][lane(64)][j(8)] sub=(d>>5)*2+((s>>4)&1),
//                                       lane=((s>>3)&1)*32+(d&31), j=s&7

// ---------------- kernel 1: convert hs + W(q,k,v) f32 -> f16 (r11) ----------
__global__ __launch_bounds__(256) void convert_kernel(
    const float4* __restrict__ hs, const float4* __restrict__ wq,
    const float4* __restrict__ wk, const float4* __restrict__ wv,
    _Float16* __restrict__ hsb, _Float16* __restrict__ wb) {
  int i = blockIdx.x * 256 + threadIdx.x;
  float4 v;
  _Float16* dst;
  if (i < 1048576) {
    v = hs[i];
    dst = hsb + (size_t)i * 4;
  } else {
    int j = i - 1048576;
    if (j < 262144) v = wq[j];
    else if (j < 524288) v = wk[j - 262144];
    else v = wv[j - 524288];
    dst = wb + (size_t)j * 4;
  }
  half4 o;
  o[0] = (_Float16)v.x; o[1] = (_Float16)v.y;
  o[2] = (_Float16)v.z; o[3] = (_Float16)v.w;
  *(half4*)dst = o;
}

// ---------------- kernel 2: QKV GEMM, 256x256, 8 waves, pipelined phases ----
// Next phase's A ds_reads issue BEFORE current phase's MFMA cluster; no
// hand-written per-phase lgkmcnt (compiler emits counted waits) -> LDS port
// and MFMA pipe overlap. One vmcnt(0)+barrier per K-tile (dbuf safety).
__global__ __launch_bounds__(512, 2) void qkv_gemm(
    const _Float16* __restrict__ A, const _Float16* __restrict__ W,
    const float* __restrict__ bq, const float* __restrict__ bk,
    const float* __restrict__ bv,
    _Float16* __restrict__ Qf, _Float16* __restrict__ Kf, _Float16* __restrict__ Vf) {
  __shared__ _Float16 sbuf[65536];   // 128KB: A[2][256][64] | B[2][256][64]
  const int tid = threadIdx.x;
  const int wv = tid >> 6;           // 0..7
  const int lane = tid & 63;
  const int g = lane >> 4;
  const int c = lane & 15;
  const int bid = blockIdx.x;        // 192 blocks: m = bid&15 -> same-m same XCD
  const int m0 = (bid & 15) * 256;
  const int n0 = (bid >> 4) * 256;
  const int wm = wv >> 2;            // 0,1  (m half)
  const int wn = wv & 3;             // 0..3 (n quarter)

  const int srow = tid >> 3;                       // 0..63
  const int sk = ((tid & 7) ^ ((tid >> 3) & 7)) * 8;
  const _Float16* aSrc = A + (size_t)(m0 + srow) * 1024 + sk;
  const _Float16* bSrc = W + (size_t)(n0 + srow) * 1024 + sk;
  char* const ldsB = (char*)&sbuf[0];

  auto STAGE_A = [&](int bf_, int k0, int grp) __attribute__((always_inline)) {
    GLDS16(aSrc + (size_t)grp * 65536 + k0,
           ldsB + bf_ * 32768 + grp * 8192 + tid * 16);
  };
  auto STAGE_B = [&](int bf_, int k0, int grp) __attribute__((always_inline)) {
    GLDS16(bSrc + (size_t)grp * 65536 + k0,
           ldsB + 65536 + bf_ * 32768 + grp * 8192 + tid * 16);
  };

  const int slot0 = ((0 * 4 + g) ^ (c & 7)) * 8;   // kk=0 chunk slot
  const int slot1 = ((4 + g) ^ (c & 7)) * 8;       // kk=1
  const int aRow = wm * 128 + c;
  const int bRow = wn * 64 + c;

  f32x4 acc[8][4];
#pragma unroll
  for (int i = 0; i < 8; ++i)
#pragma unroll
    for (int j = 0; j < 4; ++j) acc[i][j] = (f32x4){0.f, 0.f, 0.f, 0.f};

#pragma unroll
  for (int grp = 0; grp < 4; ++grp) STAGE_A(0, 0, grp);
#pragma unroll
  for (int grp = 0; grp < 4; ++grp) STAGE_B(0, 0, grp);
  asm volatile("s_waitcnt vmcnt(0)" ::: "memory");
  __builtin_amdgcn_sched_barrier(0);
  __builtin_amdgcn_s_barrier();

#define READA(dstv, ph)                                                       \
  {                                                                           \
    _Pragma("unroll") for (int mi = 0; mi < 2; ++mi) {                        \
      const int row = aRow + (2 * (ph) + mi) * 16;                            \
      dstv[mi][0] = *(const half8*)&sbuf[abase + row * 64 + slot0];           \
      dstv[mi][1] = *(const half8*)&sbuf[abase + row * 64 + slot1];           \
    }                                                                         \
  }
#define MFMAP(ph, srcv)                                                       \
  {                                                                           \
    __builtin_amdgcn_s_setprio(1);                                            \
    _Pragma("unroll") for (int nf = 0; nf < 4; ++nf)                          \
        _Pragma("unroll") for (int mi = 0; mi < 2; ++mi) {                    \
      acc[2 * (ph) + mi][nf] = __builtin_amdgcn_mfma_f32_16x16x32_f16(        \
          srcv[mi][0], bfr[nf][0], acc[2 * (ph) + mi][nf], 0, 0, 0);          \
      acc[2 * (ph) + mi][nf] = __builtin_amdgcn_mfma_f32_16x16x32_f16(        \
          srcv[mi][1], bfr[nf][1], acc[2 * (ph) + mi][nf], 0, 0, 0);          \
    }                                                                         \
    __builtin_amdgcn_s_setprio(0);                                            \
  }

  half8 bfr[4][2], aqA[2][2], aqB[2][2];
  for (int t = 0; t < 16; ++t) {
    const int bf = t & 1;
    const int abase = bf * 16384;
    const int bbase = 32768 + bf * 16384;
    const int kn = (t + 1) * 64;
    const bool st = t < 15;

#pragma unroll
    for (int nf = 0; nf < 4; ++nf) {
      bfr[nf][0] = *(const half8*)&sbuf[bbase + (bRow + nf * 16) * 64 + slot0];
      bfr[nf][1] = *(const half8*)&sbuf[bbase + (bRow + nf * 16) * 64 + slot1];
    }
    READA(aqA, 0);
    if (st) {
      STAGE_A(bf ^ 1, kn, 0); STAGE_A(bf ^ 1, kn, 1);
      STAGE_A(bf ^ 1, kn, 2); STAGE_A(bf ^ 1, kn, 3);
    }
    READA(aqB, 1);
    MFMAP(0, aqA);
    if (st) {
      STAGE_B(bf ^ 1, kn, 0); STAGE_B(bf ^ 1, kn, 1);
      STAGE_B(bf ^ 1, kn, 2); STAGE_B(bf ^ 1, kn, 3);
    }
    READA(aqA, 2);
    MFMAP(1, aqB);
    READA(aqB, 3);
    MFMAP(2, aqA);
    MFMAP(3, aqB);

    asm volatile("s_waitcnt vmcnt(0)" ::: "memory");
    __builtin_amdgcn_sched_barrier(0);
    __builtin_amdgcn_s_barrier();
  }

  const int nAbs = n0 + wn * 64;
  const int kind = nAbs >> 10;              // 0=Q 1=K 2=V
  const int nb = nAbs & 1023;
  const int head = nb >> 6;
  const float* bias = kind == 0 ? bq : (kind == 1 ? bk : bv);
  _Float16* dst = kind == 0 ? Qf : (kind == 1 ? Kf : Vf);
  _Float16* ob = &sbuf[wv * 8192];

  if (kind < 2) {
    const float scl = kind == 0 ? (0.125f * LOG2E) : 1.0f;
#pragma unroll
    for (int nf = 0; nf < 4; ++nf) {
      const int d = nf * 16 + c;
      const float bsv = bias[nb + d];
      const int base = nf * 512 + ((c >> 3) & 1) * 256 + (c & 7);
#pragma unroll
      for (int mf = 0; mf < 8; ++mf) {
#pragma unroll
        for (int r = 0; r < 4; ++r) {
          ob[(mf >> 1) * 2048 + base + (mf & 1) * 128 + g * 32 + r * 8] =
              (_Float16)((acc[mf][nf][r] + bsv) * scl);
        }
      }
    }
  } else {
#pragma unroll
    for (int nf = 0; nf < 4; ++nf) {
      const int d = nf * 16 + c;
      const float bsv = bias[nb + d];
#pragma unroll
      for (int mf = 0; mf < 8; ++mf) {
        half4 v4;
#pragma unroll
        for (int r = 0; r < 4; ++r) v4[r] = (_Float16)(acc[mf][nf][r] + bsv);
        *(half4*)&ob[(mf >> 1) * 2048 + ((nf >> 1) * 2 + (mf & 1)) * 512 +
                     ((g >> 1) * 32 + (nf & 1) * 16 + c) * 8 + (g & 1) * 4] = v4;
      }
    }
  }

  const int mRow = m0 + wm * 128;
  const int bI = mRow >> 11;
  const size_t gbase = (size_t)(bI * NHEAD + head) * 131072 +
                       (size_t)((mRow & 2047) >> 5) * 2048;
#pragma unroll
  for (int i = 0; i < 16; ++i) {
    half8 v = *(const half8*)&ob[i * 512 + lane * 8];
    *(half8*)&dst[gbase + i * 512 + lane * 8] = v;
  }
}

// ---------------- kernel 3: windowed flash attention (r13 verbatim) ---------
__global__ __launch_bounds__(256) void attn_kernel(
    const _Float16* __restrict__ Qf, const _Float16* __restrict__ Kf,
    const _Float16* __restrict__ Vf, const float* __restrict__ amask,
    float* __restrict__ out) {
  __shared__ _Float16 obuf[4][32][72];
  __shared__ float lbuf[4][32];
  const int tid = threadIdx.x;
  const int w = tid >> 6;
  const int lane = tid & 63;
  const int q31 = lane & 31;
  const int h = lane >> 5;
  const int bid = blockIdx.x;
  const int bh = bid & 31;
  const int idx = 63 - (bid >> 5);  // longest strips launch first
  const int i0 = idx * 32;
  const int bI = bh >> 4;
  const int head = bh & 15;

  const _Float16* Qh = Qf + (size_t)bh * 131072;
  const _Float16* Kh = Kf + (size_t)bh * 131072;
  const _Float16* Vh = Vf + (size_t)bh * 131072;
  const float* am = amask + (size_t)bI * S_LEN;

  const int q = i0 + q31;
  const int hiq = (q <= WINDOW) ? q : (q - WINDOW - 1);
  const int last = i0 + 31;
  const int himax = (last <= WINDOW) ? last
                    : ((i0 <= WINDOW) ? WINDOW : (last - WINDOW - 1));
  const int hiq_min = (last <= WINDOW) ? i0
                      : ((i0 > WINDOW) ? (i0 - WINDOW - 1) : 0);
  const int ntiles = (himax >> 5) + 1;
  const int nfull = (hiq_min + 1) >> 5;
  const int lim = hiq - 4 * h;

  half8 qf[4];
#pragma unroll
  for (int ch = 0; ch < 4; ++ch)
    qf[ch] = *(const half8*)&Qh[(size_t)idx * 2048 + ch * 512 + lane * 8];

  f32x16 zero16, m2init;
#pragma unroll
  for (int r = 0; r < 16; ++r) { zero16[r] = 0.f; m2init[r] = -M2_FIX; }
  f32x16 oacc0 = zero16, oacc1 = zero16;
  f32x2 lp[4];
#pragma unroll
  for (int r = 0; r < 4; ++r) lp[r] = (f32x2){0.f, 0.f};

  auto computeTile = [&](half8 k0, half8 k1, half8 k2, half8 k3,
                         half8 vf0, half8 vf1, half8 vf2, half8 vf3,
                         f32x4 am0, f32x4 am1, f32x4 am2, f32x4 am3, int t)
      __attribute__((always_inline)) {
    const int j0 = t * 32;
    f32x4 amv[4] = {am0, am1, am2, am3};

    __builtin_amdgcn_s_setprio(1);
    f32x16 st = __builtin_amdgcn_mfma_f32_32x32x16_f16(k0, qf[0], m2init, 0, 0, 0);
    st = __builtin_amdgcn_mfma_f32_32x32x16_f16(k1, qf[1], st, 0, 0, 0);
    st = __builtin_amdgcn_mfma_f32_32x32x16_f16(k2, qf[2], st, 0, 0, 0);
    st = __builtin_amdgcn_mfma_f32_32x32x16_f16(k3, qf[3], st, 0, 0, 0);
    __builtin_amdgcn_s_setprio(0);

    float p[16];
#pragma unroll
    for (int r = 0; r < 16; ++r)
      p[r] = __builtin_fmaf(amv[r >> 2][r & 3], LOG2E, st[r]);
    if (t >= nfull) {
      const int lm = lim - j0;
#pragma unroll
      for (int r = 0; r < 16; ++r) {
        const int off = (r & 3) + 8 * (r >> 2);
        p[r] = (off <= lm) ? p[r] : -3e38f;
      }
    }
#pragma unroll
    for (int r = 0; r < 16; ++r) p[r] = __builtin_amdgcn_exp2f(p[r]);
#pragma unroll
    for (int j = 0; j < 4; ++j) {
      lp[j] += (f32x2){p[2 * j], p[2 * j + 1]};
      lp[j] += (f32x2){p[8 + 2 * j], p[9 + 2 * j]};
    }

    u32 pk[8];
#pragma unroll
    for (int r = 0; r < 8; ++r) {
      auto c2 = __builtin_amdgcn_cvt_pkrtz(p[2 * r], p[2 * r + 1]);
      pk[r] = __builtin_bit_cast(u32, c2);
    }
    u32 a0 = pk[0], b0 = pk[2];
    u32 a1 = pk[1], b1 = pk[3];
    u32 a2 = pk[4], b2 = pk[6];
    u32 a3 = pk[5], b3 = pk[7];
    asm("v_permlane32_swap_b32 %0, %1" : "+v"(a0), "+v"(b0));
    asm("v_permlane32_swap_b32 %0, %1" : "+v"(a1), "+v"(b1));
    asm("v_permlane32_swap_b32 %0, %1" : "+v"(a2), "+v"(b2));
    asm("v_permlane32_swap_b32 %0, %1" : "+v"(a3), "+v"(b3));
    const half8 pf0 = __builtin_bit_cast(half8, (u32x4){a0, a1, b0, b1});
    const half8 pf1 = __builtin_bit_cast(half8, (u32x4){a2, a3, b2, b3});

    __builtin_amdgcn_s_setprio(1);
    oacc0 = __builtin_amdgcn_mfma_f32_32x32x16_f16(vf0, pf0, oacc0, 0, 0, 0);
    oacc0 = __builtin_amdgcn_mfma_f32_32x32x16_f16(vf1, pf1, oacc0, 0, 0, 0);
    oacc1 = __builtin_amdgcn_mfma_f32_32x32x16_f16(vf2, pf0, oacc1, 0, 0, 0);
    oacc1 = __builtin_amdgcn_mfma_f32_32x32x16_f16(vf3, pf1, oacc1, 0, 0, 0);
    __builtin_amdgcn_s_setprio(0);
  };

#define LOADALL(k0, k1, k2, k3, v0, v1, v2, v3, a0_, a1_, a2_, a3_, tt)  \
  {                                                                      \
    const _Float16* kt = Kh + (size_t)(tt) * 2048 + lane * 8;            \
    const _Float16* vt = Vh + (size_t)(tt) * 2048 + lane * 8;            \
    const float* at = am + (tt) * 32 + 4 * h;                            \
    k0 = *(const half8*)&kt[0];                                          \
    k1 = *(const half8*)&kt[512];                                        \
    k2 = *(const half8*)&kt[1024];                                       \
    k3 = *(const half8*)&kt[1536];                                       \
    v0 = *(const half8*)&vt[0];                                          \
    v1 = *(const half8*)&vt[512];                                        \
    v2 = *(const half8*)&vt[1024];                                       \
    v3 = *(const half8*)&vt[1536];                                       \
    a0_ = *(const f32x4*)&at[0];                                         \
    a1_ = *(const f32x4*)&at[8];                                         \
    a2_ = *(const f32x4*)&at[16];                                        \
    a3_ = *(const f32x4*)&at[24];                                        \
  }

  int t = w;
  if (t < ntiles) {
    half8 k0, k1, k2, k3, v0, v1, v2, v3;
    f32x4 a0, a1, a2, a3;
    LOADALL(k0, k1, k2, k3, v0, v1, v2, v3, a0, a1, a2, a3, t);
    int tn = t + 4;
    while (tn < ntiles) {
      half8 n0, n1, n2, n3, u0, u1, u2, u3;
      f32x4 e0, e1, e2, e3;
      LOADALL(n0, n1, n2, n3, u0, u1, u2, u3, e0, e1, e2, e3, tn);
      computeTile(k0, k1, k2, k3, v0, v1, v2, v3, a0, a1, a2, a3, t);
      k0 = n0; k1 = n1; k2 = n2; k3 = n3;
      v0 = u0; v1 = u1; v2 = u2; v3 = u3;
      a0 = e0; a1 = e1; a2 = e2; a3 = e3;
      t = tn;
      tn += 4;
    }
    computeTile(k0, k1, k2, k3, v0, v1, v2, v3, a0, a1, a2, a3, t);
  }

  f32x2 s2 = (lp[0] + lp[1]) + (lp[2] + lp[3]);
  float lw = s2[0] + s2[1];
  lw += __shfl_xor(lw, 32);
  if (h == 0) lbuf[w][q31] = lw;
#pragma unroll
  for (int j = 0; j < 4; ++j) {
    half4 h0, h1;
#pragma unroll
    for (int e = 0; e < 4; ++e) {
      h0[e] = (_Float16)oacc0[4 * j + e];
      h1[e] = (_Float16)oacc1[4 * j + e];
    }
    *(half4*)&obuf[w][q31][4 * h + 8 * j]      = h0;
    *(half4*)&obuf[w][q31][32 + 4 * h + 8 * j] = h1;
  }
  __syncthreads();

  const int mq = tid >> 3;
  const int md = (tid & 7) * 8;
  const float lt = (lbuf[0][mq] + lbuf[1][mq]) + (lbuf[2][mq] + lbuf[3][mq]);
  float s[8];
  half8 p0 = *(const half8*)&obuf[0][mq][md];
#pragma unroll
  for (int e = 0; e < 8; ++e) s[e] = (float)p0[e];
#pragma unroll
  for (int w4 = 1; w4 < 4; ++w4) {
    half8 pw = *(const half8*)&obuf[w4][mq][md];
#pragma unroll
    for (int e = 0; e < 8; ++e) s[e] += (float)pw[e];
  }
  const float inv = 1.0f / lt;
  float4 s0, s1;
  s0.x = s[0] * inv; s0.y = s[1] * inv; s0.z = s[2] * inv; s0.w = s[3] * inv;
  s1.x = s[4] * inv; s1.y = s[5] * inv; s1.z = s[6] * inv; s1.w = s[7] * inv;
  float* op = out + ((size_t)(bI * S_LEN + i0 + mq)) * 1024 + head * 64 + md;
  *(float4*)op = s0;
  *(float4*)(op + 4) = s1;
}

// ---------------- launch --------------------------------------------------
extern "C" void kernel_launch(void* const* d_in, const int* in_sizes, int n_in,
                              void* d_out, int out_size, void* d_ws, size_t ws_size,
                              hipStream_t stream) {
  const float* hs = (const float*)d_in[0];
  const float* am = (const float*)d_in[1];
  const float* Wq = (const float*)d_in[2];
  const float* bq = (const float*)d_in[3];
  const float* Wk = (const float*)d_in[4];
  const float* bk = (const float*)d_in[5];
  const float* Wv = (const float*)d_in[6];
  const float* bv = (const float*)d_in[7];
  float* out = (float*)d_out;

  char* ws = (char*)d_ws;
  _Float16* hsb = (_Float16*)(ws);
  _Float16* wb  = (_Float16*)(ws + 8388608);
  _Float16* Qf  = (_Float16*)(ws + 14680064);
  _Float16* Kf  = (_Float16*)(ws + 23068672);
  _Float16* Vf  = (_Float16*)(ws + 31457280);

  convert_kernel<<<7168, 256, 0, stream>>>(
      (const float4*)hs, (const float4*)Wq, (const float4*)Wk, (const float4*)Wv, hsb, wb);
  qkv_gemm<<<192, 512, 0, stream>>>(hsb, wb, bq, bk, bv, Qf, Kf, Vf);
  attn_kernel<<<2048, 256, 0, stream>>>(Qf, Kf, Vf, am, out);
}

// Round 23
// 68.158 us; speedup vs baseline: 1.1092x; 1.0203x over previous
//
#include <hip/hip_runtime.h>

typedef float f32x2 __attribute__((ext_vector_type(2)));
typedef float f32x4 __attribute__((ext_vector_type(4)));
typedef float f32x16 __attribute__((ext_vector_type(16)));
typedef _Float16 half8 __attribute__((ext_vector_type(8)));
typedef _Float16 half4 __attribute__((ext_vector_type(4)));
typedef unsigned int u32;
typedef u32 u32x4 __attribute__((ext_vector_type(4)));

#define S_LEN 2048
#define NHEAD 16
#define HDIM 64
#define BATCH 2
#define WINDOW 512
#define M2_FIX 5.770780163555852f   /* 4.0 * log2(e) */
#define LOG2E 1.4426950408889634f

#define GLDS16(gp, lp) __builtin_amdgcn_global_load_lds( \
    (const __attribute__((address_space(1))) void*)(gp), \
    (__attribute__((address_space(3))) void*)(lp), 16, 0, 0)

// Fragment-packed layouts (per bh = b*16+head, stride 131072 halfs):
//  Q/K tile t: [ch(4)][lane(64)][j(8)]  lane=((d>>3)&1)*32+(s&31), ch=d>>4, j=d&7
//  V   tile t: [sub(4)][lane(64)][j(8)] sub=(d>>5)*2+((s>>4)&1),
//                                       lane=((s>>3)&1)*32+(d&31), j=s&7

// ---------------- kernel 1: convert hs + W(q,k,v) f32 -> f16 (r11) ----------
__global__ __launch_bounds__(256) void convert_kernel(
    const float4* __restrict__ hs, const float4* __restrict__ wq,
    const float4* __restrict__ wk, const float4* __restrict__ wv,
    _Float16* __restrict__ hsb, _Float16* __restrict__ wb) {
  int i = blockIdx.x * 256 + threadIdx.x;
  float4 v;
  _Float16* dst;
  if (i < 1048576) {
    v = hs[i];
    dst = hsb + (size_t)i * 4;
  } else {
    int j = i - 1048576;
    if (j < 262144) v = wq[j];
    else if (j < 524288) v = wk[j - 262144];
    else v = wv[j - 524288];
    dst = wb + (size_t)j * 4;
  }
  half4 o;
  o[0] = (_Float16)v.x; o[1] = (_Float16)v.y;
  o[2] = (_Float16)v.z; o[3] = (_Float16)v.w;
  *(half4*)dst = o;
}

// ---------------- kernel 2: QKV GEMM (r19/r22 verbatim — frozen) ------------
__global__ __launch_bounds__(512, 2) void qkv_gemm(
    const _Float16* __restrict__ A, const _Float16* __restrict__ W,
    const float* __restrict__ bq, const float* __restrict__ bk,
    const float* __restrict__ bv,
    _Float16* __restrict__ Qf, _Float16* __restrict__ Kf, _Float16* __restrict__ Vf) {
  __shared__ _Float16 sbuf[65536];   // 128KB: A[2][256][64] | B[2][256][64]
  const int tid = threadIdx.x;
  const int wv = tid >> 6;           // 0..7
  const int lane = tid & 63;
  const int g = lane >> 4;
  const int c = lane & 15;
  const int bid = blockIdx.x;        // 192 blocks: m = bid&15 -> same-m same XCD
  const int m0 = (bid & 15) * 256;
  const int n0 = (bid >> 4) * 256;
  const int wm = wv >> 2;            // 0,1  (m half)
  const int wn = wv & 3;             // 0..3 (n quarter)

  const int srow = tid >> 3;                       // 0..63
  const int sk = ((tid & 7) ^ ((tid >> 3) & 7)) * 8;
  const _Float16* aSrc = A + (size_t)(m0 + srow) * 1024 + sk;
  const _Float16* bSrc = W + (size_t)(n0 + srow) * 1024 + sk;
  char* const ldsB = (char*)&sbuf[0];

  auto STAGE_A = [&](int bf_, int k0, int grp) __attribute__((always_inline)) {
    GLDS16(aSrc + (size_t)grp * 65536 + k0,
           ldsB + bf_ * 32768 + grp * 8192 + tid * 16);
  };
  auto STAGE_B = [&](int bf_, int k0, int grp) __attribute__((always_inline)) {
    GLDS16(bSrc + (size_t)grp * 65536 + k0,
           ldsB + 65536 + bf_ * 32768 + grp * 8192 + tid * 16);
  };

  const int slot0 = ((0 * 4 + g) ^ (c & 7)) * 8;   // kk=0 chunk slot
  const int slot1 = ((4 + g) ^ (c & 7)) * 8;       // kk=1
  const int aRow = wm * 128 + c;
  const int bRow = wn * 64 + c;

  f32x4 acc[8][4];
#pragma unroll
  for (int i = 0; i < 8; ++i)
#pragma unroll
    for (int j = 0; j < 4; ++j) acc[i][j] = (f32x4){0.f, 0.f, 0.f, 0.f};

#pragma unroll
  for (int grp = 0; grp < 4; ++grp) STAGE_A(0, 0, grp);
#pragma unroll
  for (int grp = 0; grp < 4; ++grp) STAGE_B(0, 0, grp);
  asm volatile("s_waitcnt vmcnt(0)" ::: "memory");
  __builtin_amdgcn_sched_barrier(0);
  __builtin_amdgcn_s_barrier();

#define READA(dstv, ph)                                                       \
  {                                                                           \
    _Pragma("unroll") for (int mi = 0; mi < 2; ++mi) {                        \
      const int row = aRow + (2 * (ph) + mi) * 16;                            \
      dstv[mi][0] = *(const half8*)&sbuf[abase + row * 64 + slot0];           \
      dstv[mi][1] = *(const half8*)&sbuf[abase + row * 64 + slot1];           \
    }                                                                         \
  }
#define MFMAP(ph, srcv)                                                       \
  {                                                                           \
    __builtin_amdgcn_s_setprio(1);                                            \
    _Pragma("unroll") for (int nf = 0; nf < 4; ++nf)                          \
        _Pragma("unroll") for (int mi = 0; mi < 2; ++mi) {                    \
      acc[2 * (ph) + mi][nf] = __builtin_amdgcn_mfma_f32_16x16x32_f16(        \
          srcv[mi][0], bfr[nf][0], acc[2 * (ph) + mi][nf], 0, 0, 0);          \
      acc[2 * (ph) + mi][nf] = __builtin_amdgcn_mfma_f32_16x16x32_f16(        \
          srcv[mi][1], bfr[nf][1], acc[2 * (ph) + mi][nf], 0, 0, 0);          \
    }                                                                         \
    __builtin_amdgcn_s_setprio(0);                                            \
  }

  half8 bfr[4][2], aqA[2][2], aqB[2][2];
  for (int t = 0; t < 16; ++t) {
    const int bf = t & 1;
    const int abase = bf * 16384;
    const int bbase = 32768 + bf * 16384;
    const int kn = (t + 1) * 64;
    const bool st = t < 15;

#pragma unroll
    for (int nf = 0; nf < 4; ++nf) {
      bfr[nf][0] = *(const half8*)&sbuf[bbase + (bRow + nf * 16) * 64 + slot0];
      bfr[nf][1] = *(const half8*)&sbuf[bbase + (bRow + nf * 16) * 64 + slot1];
    }
    READA(aqA, 0);
    if (st) {
      STAGE_A(bf ^ 1, kn, 0); STAGE_A(bf ^ 1, kn, 1);
      STAGE_A(bf ^ 1, kn, 2); STAGE_A(bf ^ 1, kn, 3);
    }
    READA(aqB, 1);
    MFMAP(0, aqA);
    if (st) {
      STAGE_B(bf ^ 1, kn, 0); STAGE_B(bf ^ 1, kn, 1);
      STAGE_B(bf ^ 1, kn, 2); STAGE_B(bf ^ 1, kn, 3);
    }
    READA(aqA, 2);
    MFMAP(1, aqB);
    READA(aqB, 3);
    MFMAP(2, aqA);
    MFMAP(3, aqB);

    asm volatile("s_waitcnt vmcnt(0)" ::: "memory");
    __builtin_amdgcn_sched_barrier(0);
    __builtin_amdgcn_s_barrier();
  }

  const int nAbs = n0 + wn * 64;
  const int kind = nAbs >> 10;              // 0=Q 1=K 2=V
  const int nb = nAbs & 1023;
  const int head = nb >> 6;
  const float* bias = kind == 0 ? bq : (kind == 1 ? bk : bv);
  _Float16* dst = kind == 0 ? Qf : (kind == 1 ? Kf : Vf);
  _Float16* ob = &sbuf[wv * 8192];

  if (kind < 2) {
    const float scl = kind == 0 ? (0.125f * LOG2E) : 1.0f;
#pragma unroll
    for (int nf = 0; nf < 4; ++nf) {
      const int d = nf * 16 + c;
      const float bsv = bias[nb + d];
      const int base = nf * 512 + ((c >> 3) & 1) * 256 + (c & 7);
#pragma unroll
      for (int mf = 0; mf < 8; ++mf) {
#pragma unroll
        for (int r = 0; r < 4; ++r) {
          ob[(mf >> 1) * 2048 + base + (mf & 1) * 128 + g * 32 + r * 8] =
              (_Float16)((acc[mf][nf][r] + bsv) * scl);
        }
      }
    }
  } else {
#pragma unroll
    for (int nf = 0; nf < 4; ++nf) {
      const int d = nf * 16 + c;
      const float bsv = bias[nb + d];
#pragma unroll
      for (int mf = 0; mf < 8; ++mf) {
        half4 v4;
#pragma unroll
        for (int r = 0; r < 4; ++r) v4[r] = (_Float16)(acc[mf][nf][r] + bsv);
        *(half4*)&ob[(mf >> 1) * 2048 + ((nf >> 1) * 2 + (mf & 1)) * 512 +
                     ((g >> 1) * 32 + (nf & 1) * 16 + c) * 8 + (g & 1) * 4] = v4;
      }
    }
  }

  const int mRow = m0 + wm * 128;
  const int bI = mRow >> 11;
  const size_t gbase = (size_t)(bI * NHEAD + head) * 131072 +
                       (size_t)((mRow & 2047) >> 5) * 2048;
#pragma unroll
  for (int i = 0; i < 16; ++i) {
    half8 v = *(const half8*)&ob[i * 512 + lane * 8];
    *(half8*)&dst[gbase + i * 512 + lane * 8] = v;
  }
}

// ---------------- kernel 3: windowed flash attention, dual-chain waves ------
// 4 waves k-split (t%4==w as before) but each wave runs TWO interleaved
// tile chains (t, t+4): chain B's issue covers chain A's latency stalls.
__global__ __launch_bounds__(256) void attn_kernel(
    const _Float16* __restrict__ Qf, const _Float16* __restrict__ Kf,
    const _Float16* __restrict__ Vf, const float* __restrict__ amask,
    float* __restrict__ out) {
  __shared__ _Float16 obuf[4][32][72];
  __shared__ float lbuf[4][32];
  const int tid = threadIdx.x;
  const int w = tid >> 6;
  const int lane = tid & 63;
  const int q31 = lane & 31;
  const int h = lane >> 5;
  const int bid = blockIdx.x;
  const int bh = bid & 31;
  const int idx = 63 - (bid >> 5);  // longest strips launch first
  const int i0 = idx * 32;
  const int bI = bh >> 4;
  const int head = bh & 15;

  const _Float16* Qh = Qf + (size_t)bh * 131072;
  const _Float16* Kh = Kf + (size_t)bh * 131072;
  const _Float16* Vh = Vf + (size_t)bh * 131072;
  const float* am = amask + (size_t)bI * S_LEN;

  const int q = i0 + q31;
  const int hiq = (q <= WINDOW) ? q : (q - WINDOW - 1);
  const int last = i0 + 31;
  const int himax = (last <= WINDOW) ? last
                    : ((i0 <= WINDOW) ? WINDOW : (last - WINDOW - 1));
  const int hiq_min = (last <= WINDOW) ? i0
                      : ((i0 > WINDOW) ? (i0 - WINDOW - 1) : 0);
  const int ntiles = (himax >> 5) + 1;
  const int nfull = (hiq_min + 1) >> 5;
  const int lim = hiq - 4 * h;

  half8 qf[4];
#pragma unroll
  for (int ch = 0; ch < 4; ++ch)
    qf[ch] = *(const half8*)&Qh[(size_t)idx * 2048 + ch * 512 + lane * 8];

  f32x16 m2init;
#pragma unroll
  for (int r = 0; r < 16; ++r) m2init[r] = -M2_FIX;
  f32x16 oacc0 = {}, oacc1 = {};
  f32x2 lp[4];
#pragma unroll
  for (int r = 0; r < 4; ++r) lp[r] = (f32x2){0.f, 0.f};

  auto QK = [&](const half8 k[4]) __attribute__((always_inline)) -> f32x16 {
    __builtin_amdgcn_s_setprio(1);
    f32x16 st = __builtin_amdgcn_mfma_f32_32x32x16_f16(k[0], qf[0], m2init, 0, 0, 0);
    st = __builtin_amdgcn_mfma_f32_32x32x16_f16(k[1], qf[1], st, 0, 0, 0);
    st = __builtin_amdgcn_mfma_f32_32x32x16_f16(k[2], qf[2], st, 0, 0, 0);
    st = __builtin_amdgcn_mfma_f32_32x32x16_f16(k[3], qf[3], st, 0, 0, 0);
    __builtin_amdgcn_s_setprio(0);
    return st;
  };
  auto SM = [&](const f32x16& st, const f32x4 amv[4], int t, float p[16])
      __attribute__((always_inline)) {
#pragma unroll
    for (int r = 0; r < 16; ++r)
      p[r] = __builtin_fmaf(amv[r >> 2][r & 3], LOG2E, st[r]);
    if (t >= nfull) {
      const int lm = lim - t * 32;
#pragma unroll
      for (int r = 0; r < 16; ++r) {
        const int off = (r & 3) + 8 * (r >> 2);
        p[r] = (off <= lm) ? p[r] : -3e38f;
      }
    }
#pragma unroll
    for (int r = 0; r < 16; ++r) p[r] = __builtin_amdgcn_exp2f(p[r]);
#pragma unroll
    for (int j = 0; j < 4; ++j) {
      lp[j] += (f32x2){p[2 * j], p[2 * j + 1]};
      lp[j] += (f32x2){p[8 + 2 * j], p[9 + 2 * j]};
    }
  };
  auto PACKF = [&](float p[16], half8& pf0, half8& pf1)
      __attribute__((always_inline)) {
    u32 pk[8];
#pragma unroll
    for (int r = 0; r < 8; ++r) {
      auto c2 = __builtin_amdgcn_cvt_pkrtz(p[2 * r], p[2 * r + 1]);
      pk[r] = __builtin_bit_cast(u32, c2);
    }
    u32 a0 = pk[0], b0 = pk[2];
    u32 a1 = pk[1], b1 = pk[3];
    u32 a2 = pk[4], b2 = pk[6];
    u32 a3 = pk[5], b3 = pk[7];
    asm("v_permlane32_swap_b32 %0, %1" : "+v"(a0), "+v"(b0));
    asm("v_permlane32_swap_b32 %0, %1" : "+v"(a1), "+v"(b1));
    asm("v_permlane32_swap_b32 %0, %1" : "+v"(a2), "+v"(b2));
    asm("v_permlane32_swap_b32 %0, %1" : "+v"(a3), "+v"(b3));
    pf0 = __builtin_bit_cast(half8, (u32x4){a0, a1, b0, b1});
    pf1 = __builtin_bit_cast(half8, (u32x4){a2, a3, b2, b3});
  };
  auto PV = [&](const half8 v[4], half8 pf0, half8 pf1)
      __attribute__((always_inline)) {
    __builtin_amdgcn_s_setprio(1);
    oacc0 = __builtin_amdgcn_mfma_f32_32x32x16_f16(v[0], pf0, oacc0, 0, 0, 0);
    oacc0 = __builtin_amdgcn_mfma_f32_32x32x16_f16(v[1], pf1, oacc0, 0, 0, 0);
    oacc1 = __builtin_amdgcn_mfma_f32_32x32x16_f16(v[2], pf0, oacc1, 0, 0, 0);
    oacc1 = __builtin_amdgcn_mfma_f32_32x32x16_f16(v[3], pf1, oacc1, 0, 0, 0);
    __builtin_amdgcn_s_setprio(0);
  };

#define LK(d, tt)                                                        \
  {                                                                      \
    const _Float16* kt = Kh + (size_t)(tt) * 2048 + lane * 8;            \
    d[0] = *(const half8*)&kt[0];                                        \
    d[1] = *(const half8*)&kt[512];                                      \
    d[2] = *(const half8*)&kt[1024];                                     \
    d[3] = *(const half8*)&kt[1536];                                     \
  }
#define LV(d, tt)                                                        \
  {                                                                      \
    const _Float16* vt = Vh + (size_t)(tt) * 2048 + lane * 8;            \
    d[0] = *(const half8*)&vt[0];                                        \
    d[1] = *(const half8*)&vt[512];                                      \
    d[2] = *(const half8*)&vt[1024];                                     \
    d[3] = *(const half8*)&vt[1536];                                     \
  }
#define LAM(d, tt)                                                       \
  {                                                                      \
    const float* at = am + (tt) * 32 + 4 * h;                            \
    d[0] = *(const f32x4*)&at[0];                                        \
    d[1] = *(const f32x4*)&at[8];                                        \
    d[2] = *(const f32x4*)&at[16];                                       \
    d[3] = *(const f32x4*)&at[24];                                       \
  }

  int t = w;
  if (t < ntiles) {
    const int cnt = (ntiles - w + 3) >> 2;   // tiles this wave handles
    half8 kA[4], kB[4], vA[4], vB[4];
    f32x4 aA[4], aB[4];
    if (cnt & 1) {
      // single-tile prologue
      LK(kA, t); LV(vA, t); LAM(aA, t);
      f32x16 st = QK(kA);
      float p[16];
      SM(st, aA, t, p);
      half8 pf0, pf1;
      PACKF(p, pf0, pf1);
      PV(vA, pf0, pf1);
      t += 4;
    }
    if (t < ntiles) {
      LK(kA, t); LK(kB, t + 4);
      for (;;) {
        const int tA = t, tB = t + 4;
        LV(vA, tA); LV(vB, tB); LAM(aA, tA); LAM(aB, tB);
        f32x16 stA = QK(kA);
        f32x16 stB = QK(kB);
        const int tn = t + 8;
        const bool more = tn < ntiles;
        half8 nkA[4], nkB[4];
        if (more) { LK(nkA, tn); LK(nkB, tn + 4); }
        float pA[16], pB[16];
        SM(stA, aA, tA, pA);
        SM(stB, aB, tB, pB);
        half8 pfA0, pfA1, pfB0, pfB1;
        PACKF(pA, pfA0, pfA1);
        PACKF(pB, pfB0, pfB1);
        PV(vA, pfA0, pfA1);
        PV(vB, pfB0, pfB1);
        if (!more) break;
#pragma unroll
        for (int e = 0; e < 4; ++e) { kA[e] = nkA[e]; kB[e] = nkB[e]; }
        t = tn;
      }
    }
  }

  f32x2 s2 = (lp[0] + lp[1]) + (lp[2] + lp[3]);
  float lw = s2[0] + s2[1];
  lw += __shfl_xor(lw, 32);
  if (h == 0) lbuf[w][q31] = lw;
#pragma unroll
  for (int j = 0; j < 4; ++j) {
    half4 h0, h1;
#pragma unroll
    for (int e = 0; e < 4; ++e) {
      h0[e] = (_Float16)oacc0[4 * j + e];
      h1[e] = (_Float16)oacc1[4 * j + e];
    }
    *(half4*)&obuf[w][q31][4 * h + 8 * j]      = h0;
    *(half4*)&obuf[w][q31][32 + 4 * h + 8 * j] = h1;
  }
  __syncthreads();

  const int mq = tid >> 3;
  const int md = (tid & 7) * 8;
  const float lt = (lbuf[0][mq] + lbuf[1][mq]) + (lbuf[2][mq] + lbuf[3][mq]);
  float s[8];
  half8 p0 = *(const half8*)&obuf[0][mq][md];
#pragma unroll
  for (int e = 0; e < 8; ++e) s[e] = (float)p0[e];
#pragma unroll
  for (int w4 = 1; w4 < 4; ++w4) {
    half8 pw = *(const half8*)&obuf[w4][mq][md];
#pragma unroll
    for (int e = 0; e < 8; ++e) s[e] += (float)pw[e];
  }
  const float inv = 1.0f / lt;
  float4 s0, s1;
  s0.x = s[0] * inv; s0.y = s[1] * inv; s0.z = s[2] * inv; s0.w = s[3] * inv;
  s1.x = s[4] * inv; s1.y = s[5] * inv; s1.z = s[6] * inv; s1.w = s[7] * inv;
  float* op = out + ((size_t)(bI * S_LEN + i0 + mq)) * 1024 + head * 64 + md;
  *(float4*)op = s0;
  *(float4*)(op + 4) = s1;
}

// ---------------- launch --------------------------------------------------
extern "C" void kernel_launch(void* const* d_in, const int* in_sizes, int n_in,
                              void* d_out, int out_size, void* d_ws, size_t ws_size,
                              hipStream_t stream) {
  const float* hs = (const float*)d_in[0];
  const float* am = (const float*)d_in[1];
  const float* Wq = (const float*)d_in[2];
  const float* bq = (const float*)d_in[3];
  const float* Wk = (const float*)d_in[4];
  const float* bk = (const float*)d_in[5];
  const float* Wv = (const float*)d_in[6];
  const float* bv = (const float*)d_in[7];
  float* out = (float*)d_out;

  char* ws = (char*)d_ws;
  _Float16* hsb = (_Float16*)(ws);
  _Float16* wb  = (_Float16*)(ws + 8388608);
  _Float16* Qf  = (_Float16*)(ws + 14680064);
  _Float16* Kf  = (_Float16*)(ws + 23068672);
  _Float16* Vf  = (_Float16*)(ws + 31457280);

  convert_kernel<<<7168, 256, 0, stream>>>(
      (const float4*)hs, (const float4*)Wq, (const float4*)Wk, (const float4*)Wv, hsb, wb);
  qkv_gemm<<<192, 512, 0, stream>>>(hsb, wb, bq, bk, bv, Qf, Kf, Vf);
  attn_kernel<<<2048, 256, 0, stream>>>(Qf, Kf, Vf, am, out);
}